// Round 1
// baseline (466.627 us; speedup 1.0000x reference)
//
#include <hip/hip_runtime.h>
#include <hip/hip_bf16.h>
#include <math.h>

// GNN influence maximizer: 2x SAGEConv(mean) + MLP head.
// N=100000 nodes, E=640000 edges, HID=128.
// Pipeline: memset ws | pack weights->bf16 swizzled | edge histogram (+scalar x agg)
//   | single-block scan -> CSR rowptr | edge scatter -> CSR col
//   | h1 = relu(rank-1 layer) bf16 | CSR gather -> mean2 bf16
//   | gemm1: h2 = [mean2|h1] @ [W2l;W2r] + b2 (K=256, mfma 16x16x32 bf16)
//   | gemm2: z = relu(h2@Wh1+bh1); out = sigmoid(z@Wh2+bh2)
// Workspace required ~81 MB.

#define N_NODES 100000
#define N_EDGES 640000

typedef unsigned short u16;
typedef unsigned int   u32;
typedef __attribute__((ext_vector_type(8))) short frag_ab;  // 8 bf16
typedef __attribute__((ext_vector_type(4))) float frag_cd;  // 4 fp32

__device__ __forceinline__ float bf2f(u16 u) {
  union { u32 i; float f; } v; v.i = ((u32)u) << 16; return v.f;
}
__device__ __forceinline__ u16 f2bf(float f) {
  union { float f; u32 i; } v; v.f = f;
  u32 u = v.i;
  return (u16)((u + 0x7FFFu + ((u >> 16) & 1u)) >> 16);  // RNE
}

// ---- pack weights: W2l/W2r -> Wt[n][k] (k=0..255), Wh1 -> Wh1t[n][k] (k=0..127)
// XOR-swizzled 16B blocks: block kb of row n stored at kb ^ (n&15). Rows unpadded,
// so a wave's b-frag ds_read_b128 lands ~2-way per bank (free).
__global__ void pack_weights(const float* __restrict__ W2l, const float* __restrict__ W2r,
                             const float* __restrict__ Wh1, u16* __restrict__ wt,
                             u16* __restrict__ wh1t) {
  int idx = blockIdx.x * 256 + threadIdx.x;
  if (idx < 32768) {                       // Wt: 128 n x 256 k
    int k = idx >> 7, n = idx & 127;
    float v = (k < 128) ? W2l[k * 128 + n] : W2r[(k - 128) * 128 + n];
    int kb = k >> 3;
    wt[n * 256 + ((kb ^ (n & 15)) * 8) + (k & 7)] = f2bf(v);
  }
  int i2 = idx - 32768;
  if (i2 >= 0 && i2 < 8192) {              // Wh1t: 64 n x 128 k
    int k = i2 >> 6, n = i2 & 63;
    float v = Wh1[k * 64 + n];
    int kb = k >> 3;
    wh1t[n * 128 + ((kb ^ (n & 15)) * 8) + (k & 7)] = f2bf(v);
  }
}

// ---- edge histogram: in-degree count + aggregate of scalar x over dst
__global__ void edge_hist(const int* __restrict__ ei, const float* __restrict__ x,
                          float* __restrict__ aggx, int* __restrict__ cnt) {
  int e = blockIdx.x * 256 + threadIdx.x;
  if (e >= N_EDGES) return;
  int s = ei[e], d = ei[N_EDGES + e];
  atomicAdd(&aggx[d], x[s]);
  atomicAdd(&cnt[d], 1);
}

// ---- single-block exclusive scan of cnt -> rowptr[N+1]
__global__ void scan_k(const int* __restrict__ cnt, int* __restrict__ rowptr) {
  __shared__ int sh[1024];
  const int T = 1024, chunk = (N_NODES + T - 1) / T;
  int t = threadIdx.x;
  int beg = t * chunk, end = min(beg + chunk, N_NODES);
  int sum = 0;
  for (int i = beg; i < end; ++i) sum += cnt[i];
  sh[t] = sum; __syncthreads();
  for (int off = 1; off < T; off <<= 1) {
    int v = (t >= off) ? sh[t - off] : 0;
    __syncthreads();
    sh[t] += v;
    __syncthreads();
  }
  int run = sh[t] - sum;                      // exclusive prefix
  for (int i = beg; i < end; ++i) { rowptr[i] = run; run += cnt[i]; }
  if (t == T - 1) rowptr[N_NODES] = sh[T - 1];
}

// ---- scatter src indices into CSR col (order within a row is arbitrary; mean is order-insensitive)
__global__ void edge_scatter(const int* __restrict__ ei, const int* __restrict__ rowptr,
                             int* __restrict__ cursor, int* __restrict__ col) {
  int e = blockIdx.x * 256 + threadIdx.x;
  if (e >= N_EDGES) return;
  int s = ei[e], d = ei[N_EDGES + e];
  int p = atomicAdd(&cursor[d], 1);
  col[rowptr[d] + p] = s;
}

// ---- layer 1: h1 = relu(mean1*W1l + x*W1r + b1), bf16 out
__global__ void h1_kernel(const float* __restrict__ x, const float* __restrict__ aggx,
                          const int* __restrict__ cnt, const float* __restrict__ W1l,
                          const float* __restrict__ W1r, const float* __restrict__ b1,
                          u16* __restrict__ h1) {
  int tid = threadIdx.x;
  int i = blockIdx.x * 2 + (tid >> 7);
  int j = tid & 127;
  if (i >= N_NODES) return;
  float mean1 = aggx[i] / fmaxf((float)cnt[i], 1.0f);
  float v = mean1 * W1l[j] + x[i] * W1r[j] + b1[j];
  h1[i * 128 + j] = f2bf(fmaxf(v, 0.0f));
}

// ---- layer-2 aggregation: one wave per node, lane handles 2 features (bf16x2)
__global__ void gather_mean(const u16* __restrict__ h1, const int* __restrict__ rowptr,
                            const int* __restrict__ col, u16* __restrict__ mean2) {
  int tid = threadIdx.x;
  int node = blockIdx.x * 4 + (tid >> 6);
  int lane = tid & 63;
  if (node >= N_NODES) return;
  int beg = rowptr[node], end = rowptr[node + 1];
  float a0 = 0.f, a1 = 0.f;
  for (int e = beg; e < end; ++e) {
    int s = col[e];
    u32 u = *(const u32*)(h1 + s * 128 + lane * 2);   // 256 B coalesced per wave
    a0 += bf2f((u16)(u & 0xffff));
    a1 += bf2f((u16)(u >> 16));
  }
  float inv = 1.0f / fmaxf((float)(end - beg), 1.0f);
  u32 w = (u32)f2bf(a0 * inv) | ((u32)f2bf(a1 * inv) << 16);
  *(u32*)(mean2 + node * 128 + lane * 2) = w;
}

// ---- gemm1: h2[N,128] = [mean2|h1] @ Wt(256x128) + b2, bf16 out
// 4 waves x (2 m-tiles of 16 rows) = 128 rows/block; 8 col-tiles; K=256 in 8 steps.
__global__ __launch_bounds__(256) void gemm1(const u16* __restrict__ mean2,
                                             const u16* __restrict__ h1,
                                             const u16* __restrict__ wt_g,
                                             const float* __restrict__ b2,
                                             u16* __restrict__ h2g) {
  __shared__ u16 wt[32768];  // 64 KB swizzled [n][k]
  int tid = threadIdx.x;
  {
    const uint4* s = (const uint4*)wt_g;
    uint4* d = (uint4*)wt;
    for (int i = tid; i < 4096; i += 256) d[i] = s[i];
  }
  __syncthreads();
  int w = tid >> 6, lane = tid & 63;
  int n15 = lane & 15, q = lane >> 4;
  int blockRow = blockIdx.x * 128;
  frag_cd zero = {0.f, 0.f, 0.f, 0.f};
  frag_cd acc[2][8];
#pragma unroll
  for (int mt = 0; mt < 2; ++mt)
#pragma unroll
    for (int ct = 0; ct < 8; ++ct) acc[mt][ct] = zero;
  int arow[2];
#pragma unroll
  for (int mt = 0; mt < 2; ++mt) {
    int r = blockRow + w * 32 + mt * 16 + n15;   // A-frag: m = lane&15
    arow[mt] = (r < N_NODES) ? r : (N_NODES - 1);
  }
#pragma unroll
  for (int ks = 0; ks < 8; ++ks) {
    const u16* abase = (ks < 4) ? (mean2 + ks * 32) : (h1 + (ks - 4) * 32);
    frag_ab a[2];
#pragma unroll
    for (int mt = 0; mt < 2; ++mt)
      a[mt] = *(const frag_ab*)(abase + (size_t)arow[mt] * 128 + q * 8);  // k = q*8+j
#pragma unroll
    for (int ct = 0; ct < 8; ++ct) {
      int off = (ct * 16 + n15) * 256 + (((ks * 4 + q) ^ n15) * 8);
      frag_ab b = *(const frag_ab*)(wt + off);
#pragma unroll
      for (int mt = 0; mt < 2; ++mt)
        acc[mt][ct] = __builtin_amdgcn_mfma_f32_16x16x32_bf16(a[mt], b, acc[mt][ct], 0, 0, 0);
    }
  }
  // epilogue: C/D layout col=lane&15, row=q*4+r
#pragma unroll
  for (int ct = 0; ct < 8; ++ct) {
    int colg = ct * 16 + n15;
    float bias = b2[colg];
#pragma unroll
    for (int mt = 0; mt < 2; ++mt) {
      int rbase = blockRow + w * 32 + mt * 16 + q * 4;
#pragma unroll
      for (int r = 0; r < 4; ++r) {
        int row = rbase + r;
        if (row < N_NODES) h2g[(size_t)row * 128 + colg] = f2bf(acc[mt][ct][r] + bias);
      }
    }
  }
}

// ---- gemm2: z = relu(h2@Wh1+bh1) [128x64 per block], out = sigmoid(z@Wh2+bh2)
__global__ __launch_bounds__(256) void gemm2(const u16* __restrict__ h2g,
                                             const u16* __restrict__ wh1t_g,
                                             const float* __restrict__ bh1,
                                             const float* __restrict__ Wh2,
                                             const float* __restrict__ bh2,
                                             float* __restrict__ out) {
  __shared__ u16 wh[8192];        // 16 KB swizzled [n][k]
  __shared__ u16 zt[128 * 68];    // z tile, row stride 68 bf16
  __shared__ float wh2s[64];
  int tid = threadIdx.x;
  {
    const uint4* s = (const uint4*)wh1t_g;
    uint4* d = (uint4*)wh;
    for (int i = tid; i < 1024; i += 256) d[i] = s[i];
  }
  if (tid < 64) wh2s[tid] = Wh2[tid];
  __syncthreads();
  int w = tid >> 6, lane = tid & 63;
  int n15 = lane & 15, q = lane >> 4;
  int blockRow = blockIdx.x * 128;
  frag_cd zero = {0.f, 0.f, 0.f, 0.f};
  frag_cd acc[2][4];
#pragma unroll
  for (int mt = 0; mt < 2; ++mt)
#pragma unroll
    for (int ct = 0; ct < 4; ++ct) acc[mt][ct] = zero;
  int arow[2];
#pragma unroll
  for (int mt = 0; mt < 2; ++mt) {
    int r = blockRow + w * 32 + mt * 16 + n15;
    arow[mt] = (r < N_NODES) ? r : (N_NODES - 1);
  }
#pragma unroll
  for (int ks = 0; ks < 4; ++ks) {
    frag_ab a[2];
#pragma unroll
    for (int mt = 0; mt < 2; ++mt)
      a[mt] = *(const frag_ab*)(h2g + (size_t)arow[mt] * 128 + ks * 32 + q * 8);
#pragma unroll
    for (int ct = 0; ct < 4; ++ct) {
      int off = (ct * 16 + n15) * 128 + (((ks * 4 + q) ^ n15) * 8);
      frag_ab b = *(const frag_ab*)(wh + off);
#pragma unroll
      for (int mt = 0; mt < 2; ++mt)
        acc[mt][ct] = __builtin_amdgcn_mfma_f32_16x16x32_bf16(a[mt], b, acc[mt][ct], 0, 0, 0);
    }
  }
#pragma unroll
  for (int ct = 0; ct < 4; ++ct) {
    int colg = ct * 16 + n15;
    float bias = bh1[colg];
#pragma unroll
    for (int mt = 0; mt < 2; ++mt) {
      int rl = w * 32 + mt * 16 + q * 4;
#pragma unroll
      for (int r = 0; r < 4; ++r)
        zt[(rl + r) * 68 + colg] = f2bf(fmaxf(acc[mt][ct][r] + bias, 0.0f));
    }
  }
  __syncthreads();
  if (tid < 128) {
    int row = blockRow + tid;
    if (row < N_NODES) {
      float s = bh2[0];
#pragma unroll
      for (int k = 0; k < 64; ++k) s += bf2f(zt[tid * 68 + k]) * wh2s[k];
      out[row] = 1.0f / (1.0f + expf(-s));
    }
  }
}

extern "C" void kernel_launch(void* const* d_in, const int* in_sizes, int n_in,
                              void* d_out, int out_size, void* d_ws, size_t ws_size,
                              hipStream_t stream) {
  const float* x   = (const float*)d_in[0];
  const int*   ei  = (const int*)d_in[1];
  const float* W1l = (const float*)d_in[2];
  const float* W1r = (const float*)d_in[3];
  const float* b1  = (const float*)d_in[4];
  const float* W2l = (const float*)d_in[5];
  const float* W2r = (const float*)d_in[6];
  const float* b2  = (const float*)d_in[7];
  const float* Wh1 = (const float*)d_in[8];
  const float* bh1 = (const float*)d_in[9];
  const float* Wh2 = (const float*)d_in[10];
  const float* bh2 = (const float*)d_in[11];
  float* out = (float*)d_out;

  char* ws = (char*)d_ws;
  size_t off = 0;
  auto alloc = [&](size_t bytes) -> char* {
    char* p = ws + off;
    off += (bytes + 255) & ~(size_t)255;
    return p;
  };
  int*   cnt    = (int*)alloc(N_NODES * 4);
  float* aggx   = (float*)alloc(N_NODES * 4);
  int*   cursor = (int*)alloc(N_NODES * 4);
  size_t zero_bytes = off;                      // cnt+aggx+cursor contiguous
  int*   rowptr = (int*)alloc((N_NODES + 1) * 4);
  int*   col    = (int*)alloc(N_EDGES * 4);
  u16*   h1     = (u16*)alloc((size_t)N_NODES * 128 * 2);
  u16*   mean2  = (u16*)alloc((size_t)N_NODES * 128 * 2);
  u16*   h2g    = (u16*)alloc((size_t)N_NODES * 128 * 2);
  u16*   wt     = (u16*)alloc(65536);
  u16*   wh1t   = (u16*)alloc(16384);
  (void)ws_size; (void)in_sizes; (void)n_in; (void)out_size;

  hipMemsetAsync(ws, 0, zero_bytes, stream);
  pack_weights<<<160, 256, 0, stream>>>(W2l, W2r, Wh1, wt, wh1t);
  edge_hist<<<(N_EDGES + 255) / 256, 256, 0, stream>>>(ei, x, aggx, cnt);
  scan_k<<<1, 1024, 0, stream>>>(cnt, rowptr);
  edge_scatter<<<(N_EDGES + 255) / 256, 256, 0, stream>>>(ei, rowptr, cursor, col);
  h1_kernel<<<(N_NODES + 1) / 2, 256, 0, stream>>>(x, aggx, cnt, W1l, W1r, b1, h1);
  gather_mean<<<(N_NODES + 3) / 4, 256, 0, stream>>>(h1, rowptr, col, mean2);
  gemm1<<<(N_NODES + 127) / 128, 256, 0, stream>>>(mean2, h1, wt, b2, h2g);
  gemm2<<<(N_NODES + 127) / 128, 256, 0, stream>>>(h2g, wh1t, bh1, Wh2, bh2, out);
}

// Round 2
// 315.168 us; speedup vs baseline: 1.4806x; 1.4806x over previous
//
#include <hip/hip_runtime.h>
#include <hip/hip_bf16.h>
#include <math.h>

// GNN influence maximizer: 2x SAGEConv(mean) + MLP head.
// N=100000 nodes, E=640000 edges, HID=128.
// R2: replaced single-block scan_k (160us, 0.16% occupancy) with 3-pass
// hierarchical scan (reduce -> scan partials -> rescan+offset).

#define N_NODES 100000
#define N_EDGES 640000
#define NBLK ((N_NODES + 255) / 256)   // 391 scan blocks

typedef unsigned short u16;
typedef unsigned int   u32;
typedef __attribute__((ext_vector_type(8))) short frag_ab;  // 8 bf16
typedef __attribute__((ext_vector_type(4))) float frag_cd;  // 4 fp32

__device__ __forceinline__ float bf2f(u16 u) {
  union { u32 i; float f; } v; v.i = ((u32)u) << 16; return v.f;
}
__device__ __forceinline__ u16 f2bf(float f) {
  union { float f; u32 i; } v; v.f = f;
  u32 u = v.i;
  return (u16)((u + 0x7FFFu + ((u >> 16) & 1u)) >> 16);  // RNE
}

// ---- pack weights: W2l/W2r -> Wt[n][k] (k=0..255), Wh1 -> Wh1t[n][k] (k=0..127)
// XOR-swizzled 16B blocks: block kb of row n stored at kb ^ (n&15).
__global__ void pack_weights(const float* __restrict__ W2l, const float* __restrict__ W2r,
                             const float* __restrict__ Wh1, u16* __restrict__ wt,
                             u16* __restrict__ wh1t) {
  int idx = blockIdx.x * 256 + threadIdx.x;
  if (idx < 32768) {                       // Wt: 128 n x 256 k
    int k = idx >> 7, n = idx & 127;
    float v = (k < 128) ? W2l[k * 128 + n] : W2r[(k - 128) * 128 + n];
    int kb = k >> 3;
    wt[n * 256 + ((kb ^ (n & 15)) * 8) + (k & 7)] = f2bf(v);
  }
  int i2 = idx - 32768;
  if (i2 >= 0 && i2 < 8192) {              // Wh1t: 64 n x 128 k
    int k = i2 >> 6, n = i2 & 63;
    float v = Wh1[k * 64 + n];
    int kb = k >> 3;
    wh1t[n * 128 + ((kb ^ (n & 15)) * 8) + (k & 7)] = f2bf(v);
  }
}

// ---- edge histogram: in-degree count + aggregate of scalar x over dst
__global__ void edge_hist(const int* __restrict__ ei, const float* __restrict__ x,
                          float* __restrict__ aggx, int* __restrict__ cnt) {
  int e = blockIdx.x * 256 + threadIdx.x;
  if (e >= N_EDGES) return;
  int s = ei[e], d = ei[N_EDGES + e];
  atomicAdd(&aggx[d], x[s]);
  atomicAdd(&cnt[d], 1);
}

// ---- scan pass 1: per-block reduction of 256 counts -> bsum[block]
__global__ __launch_bounds__(256) void scan_pass1(const int* __restrict__ cnt,
                                                  int* __restrict__ bsum) {
  int t = threadIdx.x, b = blockIdx.x;
  int i = b * 256 + t;
  int v = (i < N_NODES) ? cnt[i] : 0;
#pragma unroll
  for (int off = 32; off > 0; off >>= 1) v += __shfl_down(v, off, 64);
  __shared__ int ws[4];
  if ((t & 63) == 0) ws[t >> 6] = v;
  __syncthreads();
  if (t == 0) bsum[b] = ws[0] + ws[1] + ws[2] + ws[3];
}

// ---- scan pass 2: single block scans NBLK(=391) block sums -> exclusive bpre, total
__global__ __launch_bounds__(512) void scan_partials(const int* __restrict__ bsum,
                                                     int* __restrict__ bpre,
                                                     int* __restrict__ rowptr) {
  int t = threadIdx.x;                      // 512 threads >= NBLK
  int v = (t < NBLK) ? bsum[t] : 0;
  int lane = t & 63, w = t >> 6;
  int x = v;
#pragma unroll
  for (int off = 1; off < 64; off <<= 1) {
    int y = __shfl_up(x, off, 64);
    if (lane >= off) x += y;
  }
  __shared__ int ws[8];
  if (lane == 63) ws[w] = x;
  __syncthreads();
  int wo = 0;
  for (int k = 0; k < w; ++k) wo += ws[k];
  int incl = x + wo;
  if (t < NBLK) bpre[t] = incl - v;
  if (t == 511) rowptr[N_NODES] = incl;     // padding lanes add 0 -> total
}

// ---- scan pass 3: in-block exclusive scan + block prefix -> rowptr
__global__ __launch_bounds__(256) void scan_pass3(const int* __restrict__ cnt,
                                                  const int* __restrict__ bpre,
                                                  int* __restrict__ rowptr) {
  int t = threadIdx.x, b = blockIdx.x;
  int i = b * 256 + t;
  int v = (i < N_NODES) ? cnt[i] : 0;
  int lane = t & 63, w = t >> 6;
  int x = v;
#pragma unroll
  for (int off = 1; off < 64; off <<= 1) {
    int y = __shfl_up(x, off, 64);
    if (lane >= off) x += y;
  }
  __shared__ int ws[4];
  if (lane == 63) ws[w] = x;
  __syncthreads();
  int wo = 0;
  for (int k = 0; k < w; ++k) wo += ws[k];
  if (i < N_NODES) rowptr[i] = bpre[b] + (x + wo - v);
}

// ---- scatter src indices into CSR col (order within a row arbitrary; mean is order-insensitive)
__global__ void edge_scatter(const int* __restrict__ ei, const int* __restrict__ rowptr,
                             int* __restrict__ cursor, int* __restrict__ col) {
  int e = blockIdx.x * 256 + threadIdx.x;
  if (e >= N_EDGES) return;
  int s = ei[e], d = ei[N_EDGES + e];
  int p = atomicAdd(&cursor[d], 1);
  col[rowptr[d] + p] = s;
}

// ---- layer 1: h1 = relu(mean1*W1l + x*W1r + b1), bf16 out
__global__ void h1_kernel(const float* __restrict__ x, const float* __restrict__ aggx,
                          const int* __restrict__ cnt, const float* __restrict__ W1l,
                          const float* __restrict__ W1r, const float* __restrict__ b1,
                          u16* __restrict__ h1) {
  int tid = threadIdx.x;
  int i = blockIdx.x * 2 + (tid >> 7);
  int j = tid & 127;
  if (i >= N_NODES) return;
  float mean1 = aggx[i] / fmaxf((float)cnt[i], 1.0f);
  float v = mean1 * W1l[j] + x[i] * W1r[j] + b1[j];
  h1[i * 128 + j] = f2bf(fmaxf(v, 0.0f));
}

// ---- layer-2 aggregation: one wave per node, lane handles 2 features (bf16x2)
__global__ void gather_mean(const u16* __restrict__ h1, const int* __restrict__ rowptr,
                            const int* __restrict__ col, u16* __restrict__ mean2) {
  int tid = threadIdx.x;
  int node = blockIdx.x * 4 + (tid >> 6);
  int lane = tid & 63;
  if (node >= N_NODES) return;
  int beg = rowptr[node], end = rowptr[node + 1];
  float a0 = 0.f, a1 = 0.f;
  for (int e = beg; e < end; ++e) {
    int s = col[e];
    u32 u = *(const u32*)(h1 + s * 128 + lane * 2);   // 256 B coalesced per wave
    a0 += bf2f((u16)(u & 0xffff));
    a1 += bf2f((u16)(u >> 16));
  }
  float inv = 1.0f / fmaxf((float)(end - beg), 1.0f);
  u32 w = (u32)f2bf(a0 * inv) | ((u32)f2bf(a1 * inv) << 16);
  *(u32*)(mean2 + node * 128 + lane * 2) = w;
}

// ---- gemm1: h2[N,128] = [mean2|h1] @ Wt(256x128) + b2, bf16 out
__global__ __launch_bounds__(256) void gemm1(const u16* __restrict__ mean2,
                                             const u16* __restrict__ h1,
                                             const u16* __restrict__ wt_g,
                                             const float* __restrict__ b2,
                                             u16* __restrict__ h2g) {
  __shared__ u16 wt[32768];  // 64 KB swizzled [n][k]
  int tid = threadIdx.x;
  {
    const uint4* s = (const uint4*)wt_g;
    uint4* d = (uint4*)wt;
    for (int i = tid; i < 4096; i += 256) d[i] = s[i];
  }
  __syncthreads();
  int w = tid >> 6, lane = tid & 63;
  int n15 = lane & 15, q = lane >> 4;
  int blockRow = blockIdx.x * 128;
  frag_cd zero = {0.f, 0.f, 0.f, 0.f};
  frag_cd acc[2][8];
#pragma unroll
  for (int mt = 0; mt < 2; ++mt)
#pragma unroll
    for (int ct = 0; ct < 8; ++ct) acc[mt][ct] = zero;
  int arow[2];
#pragma unroll
  for (int mt = 0; mt < 2; ++mt) {
    int r = blockRow + w * 32 + mt * 16 + n15;   // A-frag: m = lane&15
    arow[mt] = (r < N_NODES) ? r : (N_NODES - 1);
  }
#pragma unroll
  for (int ks = 0; ks < 8; ++ks) {
    const u16* abase = (ks < 4) ? (mean2 + ks * 32) : (h1 + (ks - 4) * 32);
    frag_ab a[2];
#pragma unroll
    for (int mt = 0; mt < 2; ++mt)
      a[mt] = *(const frag_ab*)(abase + (size_t)arow[mt] * 128 + q * 8);  // k = q*8+j
#pragma unroll
    for (int ct = 0; ct < 8; ++ct) {
      int off = (ct * 16 + n15) * 256 + (((ks * 4 + q) ^ n15) * 8);
      frag_ab b = *(const frag_ab*)(wt + off);
#pragma unroll
      for (int mt = 0; mt < 2; ++mt)
        acc[mt][ct] = __builtin_amdgcn_mfma_f32_16x16x32_bf16(a[mt], b, acc[mt][ct], 0, 0, 0);
    }
  }
  // epilogue: C/D layout col=lane&15, row=q*4+r
#pragma unroll
  for (int ct = 0; ct < 8; ++ct) {
    int colg = ct * 16 + n15;
    float bias = b2[colg];
#pragma unroll
    for (int mt = 0; mt < 2; ++mt) {
      int rbase = blockRow + w * 32 + mt * 16 + q * 4;
#pragma unroll
      for (int r = 0; r < 4; ++r) {
        int row = rbase + r;
        if (row < N_NODES) h2g[(size_t)row * 128 + colg] = f2bf(acc[mt][ct][r] + bias);
      }
    }
  }
}

// ---- gemm2: z = relu(h2@Wh1+bh1) [128x64 per block], out = sigmoid(z@Wh2+bh2)
__global__ __launch_bounds__(256) void gemm2(const u16* __restrict__ h2g,
                                             const u16* __restrict__ wh1t_g,
                                             const float* __restrict__ bh1,
                                             const float* __restrict__ Wh2,
                                             const float* __restrict__ bh2,
                                             float* __restrict__ out) {
  __shared__ u16 wh[8192];        // 16 KB swizzled [n][k]
  __shared__ u16 zt[128 * 68];    // z tile, row stride 68 bf16
  __shared__ float wh2s[64];
  int tid = threadIdx.x;
  {
    const uint4* s = (const uint4*)wh1t_g;
    uint4* d = (uint4*)wh;
    for (int i = tid; i < 1024; i += 256) d[i] = s[i];
  }
  if (tid < 64) wh2s[tid] = Wh2[tid];
  __syncthreads();
  int w = tid >> 6, lane = tid & 63;
  int n15 = lane & 15, q = lane >> 4;
  int blockRow = blockIdx.x * 128;
  frag_cd zero = {0.f, 0.f, 0.f, 0.f};
  frag_cd acc[2][4];
#pragma unroll
  for (int mt = 0; mt < 2; ++mt)
#pragma unroll
    for (int ct = 0; ct < 4; ++ct) acc[mt][ct] = zero;
  int arow[2];
#pragma unroll
  for (int mt = 0; mt < 2; ++mt) {
    int r = blockRow + w * 32 + mt * 16 + n15;
    arow[mt] = (r < N_NODES) ? r : (N_NODES - 1);
  }
#pragma unroll
  for (int ks = 0; ks < 4; ++ks) {
    frag_ab a[2];
#pragma unroll
    for (int mt = 0; mt < 2; ++mt)
      a[mt] = *(const frag_ab*)(h2g + (size_t)arow[mt] * 128 + ks * 32 + q * 8);
#pragma unroll
    for (int ct = 0; ct < 4; ++ct) {
      int off = (ct * 16 + n15) * 128 + (((ks * 4 + q) ^ n15) * 8);
      frag_ab b = *(const frag_ab*)(wh + off);
#pragma unroll
      for (int mt = 0; mt < 2; ++mt)
        acc[mt][ct] = __builtin_amdgcn_mfma_f32_16x16x32_bf16(a[mt], b, acc[mt][ct], 0, 0, 0);
    }
  }
#pragma unroll
  for (int ct = 0; ct < 4; ++ct) {
    int colg = ct * 16 + n15;
    float bias = bh1[colg];
#pragma unroll
    for (int mt = 0; mt < 2; ++mt) {
      int rl = w * 32 + mt * 16 + q * 4;
#pragma unroll
      for (int r = 0; r < 4; ++r)
        zt[(rl + r) * 68 + colg] = f2bf(fmaxf(acc[mt][ct][r] + bias, 0.0f));
    }
  }
  __syncthreads();
  if (tid < 128) {
    int row = blockRow + tid;
    if (row < N_NODES) {
      float s = bh2[0];
#pragma unroll
      for (int k = 0; k < 64; ++k) s += bf2f(zt[tid * 68 + k]) * wh2s[k];
      out[row] = 1.0f / (1.0f + expf(-s));
    }
  }
}

extern "C" void kernel_launch(void* const* d_in, const int* in_sizes, int n_in,
                              void* d_out, int out_size, void* d_ws, size_t ws_size,
                              hipStream_t stream) {
  const float* x   = (const float*)d_in[0];
  const int*   ei  = (const int*)d_in[1];
  const float* W1l = (const float*)d_in[2];
  const float* W1r = (const float*)d_in[3];
  const float* b1  = (const float*)d_in[4];
  const float* W2l = (const float*)d_in[5];
  const float* W2r = (const float*)d_in[6];
  const float* b2  = (const float*)d_in[7];
  const float* Wh1 = (const float*)d_in[8];
  const float* bh1 = (const float*)d_in[9];
  const float* Wh2 = (const float*)d_in[10];
  const float* bh2 = (const float*)d_in[11];
  float* out = (float*)d_out;

  char* ws = (char*)d_ws;
  size_t off = 0;
  auto alloc = [&](size_t bytes) -> char* {
    char* p = ws + off;
    off += (bytes + 255) & ~(size_t)255;
    return p;
  };
  int*   cnt    = (int*)alloc(N_NODES * 4);
  float* aggx   = (float*)alloc(N_NODES * 4);
  int*   cursor = (int*)alloc(N_NODES * 4);
  size_t zero_bytes = off;                      // cnt+aggx+cursor contiguous
  int*   rowptr = (int*)alloc((N_NODES + 1) * 4);
  int*   col    = (int*)alloc(N_EDGES * 4);
  int*   bsum   = (int*)alloc(NBLK * 4);
  int*   bpre   = (int*)alloc(NBLK * 4);
  u16*   h1     = (u16*)alloc((size_t)N_NODES * 128 * 2);
  u16*   mean2  = (u16*)alloc((size_t)N_NODES * 128 * 2);
  u16*   h2g    = (u16*)alloc((size_t)N_NODES * 128 * 2);
  u16*   wt     = (u16*)alloc(65536);
  u16*   wh1t   = (u16*)alloc(16384);
  (void)ws_size; (void)in_sizes; (void)n_in; (void)out_size;

  hipMemsetAsync(ws, 0, zero_bytes, stream);
  pack_weights<<<160, 256, 0, stream>>>(W2l, W2r, Wh1, wt, wh1t);
  edge_hist<<<(N_EDGES + 255) / 256, 256, 0, stream>>>(ei, x, aggx, cnt);
  scan_pass1<<<NBLK, 256, 0, stream>>>(cnt, bsum);
  scan_partials<<<1, 512, 0, stream>>>(bsum, bpre, rowptr);
  scan_pass3<<<NBLK, 256, 0, stream>>>(cnt, bpre, rowptr);
  edge_scatter<<<(N_EDGES + 255) / 256, 256, 0, stream>>>(ei, rowptr, cursor, col);
  h1_kernel<<<(N_NODES + 1) / 2, 256, 0, stream>>>(x, aggx, cnt, W1l, W1r, b1, h1);
  gather_mean<<<(N_NODES + 3) / 4, 256, 0, stream>>>(h1, rowptr, col, mean2);
  gemm1<<<(N_NODES + 127) / 128, 256, 0, stream>>>(mean2, h1, wt, b2, h2g);
  gemm2<<<(N_NODES + 127) / 128, 256, 0, stream>>>(h2g, wh1t, bh1, Wh2, bh2, out);
}

// Round 3
// 278.493 us; speedup vs baseline: 1.6755x; 1.1317x over previous
//
#include <hip/hip_runtime.h>
#include <hip/hip_bf16.h>
#include <math.h>

// GNN influence maximizer: 2x SAGEConv(mean) + MLP head.
// N=100000, E=640000, HID=128.
// R3: rank-2 insight — h1 row = relu(m1*W1l + x*W1r + b1) is a function of 2
// scalars/node. Gather 4B scalar pairs instead of 256B rows; never materialize
// h1. Fuse gather + gemm1 + head into one megaG kernel (LDS tile round-trips).
// 7 dispatches: memset | hist+pack | scan1 | scan2 | scan3+scp | scatter | megaG.

#define N_NODES 100000
#define N_EDGES 640000
#define NBLK ((N_NODES + 255) / 256)   // 391
#define HIST_BLOCKS ((N_EDGES + 255) / 256)  // 2500

typedef unsigned short u16;
typedef unsigned int   u32;
typedef __attribute__((ext_vector_type(8))) short frag_ab;  // 8 bf16
typedef __attribute__((ext_vector_type(4))) float frag_cd;  // 4 fp32

__device__ __forceinline__ float bf2f(u16 u) {
  union { u32 i; float f; } v; v.i = ((u32)u) << 16; return v.f;
}
__device__ __forceinline__ u16 f2bf(float f) {
  union { float f; u32 i; } v; v.f = f;
  u32 u = v.i;
  return (u16)((u + 0x7FFFu + ((u >> 16) & 1u)) >> 16);  // RNE
}

// ---- hist (blocks < HIST_BLOCKS) + weight pack (remaining blocks)
// wt: [n][k] plain bf16, k<128 -> W2l, else W2r. wh1t: [n][k] plain bf16.
__global__ void hist_pack(const int* __restrict__ ei, const float* __restrict__ x,
                          const float* __restrict__ W2l, const float* __restrict__ W2r,
                          const float* __restrict__ Wh1,
                          float* __restrict__ aggx, int* __restrict__ cnt,
                          u16* __restrict__ wt, u16* __restrict__ wh1t) {
  int b = blockIdx.x;
  if (b < HIST_BLOCKS) {
    int e = b * 256 + threadIdx.x;
    if (e >= N_EDGES) return;
    int s = ei[e], d = ei[N_EDGES + e];
    atomicAdd(&aggx[d], x[s]);
    atomicAdd(&cnt[d], 1);
  } else {
    int idx = (b - HIST_BLOCKS) * 256 + threadIdx.x;
    if (idx < 32768) {                     // wt: 128 n x 256 k
      int k = idx >> 7, n = idx & 127;
      float v = (k < 128) ? W2l[k * 128 + n] : W2r[(k - 128) * 128 + n];
      wt[n * 256 + k] = f2bf(v);
    }
    int i2 = idx - 32768;
    if (i2 >= 0 && i2 < 8192) {            // wh1t: 64 n x 128 k
      int k = i2 >> 6, n = i2 & 63;
      wh1t[n * 128 + k] = f2bf(Wh1[k * 64 + n]);
    }
  }
}

// ---- scan pass 1: per-block reduction of 256 counts -> bsum[block]
__global__ __launch_bounds__(256) void scan_pass1(const int* __restrict__ cnt,
                                                  int* __restrict__ bsum) {
  int t = threadIdx.x, b = blockIdx.x;
  int i = b * 256 + t;
  int v = (i < N_NODES) ? cnt[i] : 0;
#pragma unroll
  for (int off = 32; off > 0; off >>= 1) v += __shfl_down(v, off, 64);
  __shared__ int ws[4];
  if ((t & 63) == 0) ws[t >> 6] = v;
  __syncthreads();
  if (t == 0) bsum[b] = ws[0] + ws[1] + ws[2] + ws[3];
}

// ---- scan pass 2: single block scans NBLK block sums -> exclusive bpre, total
__global__ __launch_bounds__(512) void scan_partials(const int* __restrict__ bsum,
                                                     int* __restrict__ bpre,
                                                     int* __restrict__ rowptr) {
  int t = threadIdx.x;
  int v = (t < NBLK) ? bsum[t] : 0;
  int lane = t & 63, w = t >> 6;
  int x = v;
#pragma unroll
  for (int off = 1; off < 64; off <<= 1) {
    int y = __shfl_up(x, off, 64);
    if (lane >= off) x += y;
  }
  __shared__ int ws[8];
  if (lane == 63) ws[w] = x;
  __syncthreads();
  int wo = 0;
  for (int k = 0; k < w; ++k) wo += ws[k];
  int incl = x + wo;
  if (t < NBLK) bpre[t] = incl - v;
  if (t == 511) rowptr[N_NODES] = incl;
}

// ---- scan pass 3 (blocks < NBLK) + scalar-pair table scp (remaining blocks)
// scp[i] = packed bf16 (m1_i = aggx/max(cnt,1), x_i)
__global__ __launch_bounds__(256) void scan3_scp(const int* __restrict__ cnt,
                                                 const int* __restrict__ bpre,
                                                 const float* __restrict__ aggx,
                                                 const float* __restrict__ x,
                                                 int* __restrict__ rowptr,
                                                 u32* __restrict__ scp) {
  int b = blockIdx.x, t = threadIdx.x;
  if (b < NBLK) {
    int i = b * 256 + t;
    int v = (i < N_NODES) ? cnt[i] : 0;
    int lane = t & 63, w = t >> 6;
    int xx = v;
#pragma unroll
    for (int off = 1; off < 64; off <<= 1) {
      int y = __shfl_up(xx, off, 64);
      if (lane >= off) xx += y;
    }
    __shared__ int ws[4];
    if (lane == 63) ws[w] = xx;
    __syncthreads();
    int wo = 0;
    for (int k = 0; k < w; ++k) wo += ws[k];
    if (i < N_NODES) rowptr[i] = bpre[b] + (xx + wo - v);
  } else {
    int i = (b - NBLK) * 256 + t;
    if (i < N_NODES) {
      float m1 = aggx[i] / fmaxf((float)cnt[i], 1.0f);
      scp[i] = (u32)f2bf(m1) | ((u32)f2bf(x[i]) << 16);
    }
  }
}

// ---- scatter src indices into CSR col
__global__ void edge_scatter(const int* __restrict__ ei, const int* __restrict__ rowptr,
                             int* __restrict__ cursor, int* __restrict__ col) {
  int e = blockIdx.x * 256 + threadIdx.x;
  if (e >= N_EDGES) return;
  int s = ei[e], d = ei[N_EDGES + e];
  int p = atomicAdd(&cursor[d], 1);
  col[rowptr[d] + p] = s;
}

// ---- megaG: per block of 128 nodes:
//  phase1: scalar-pair gather -> mean2 tile in LDS (bf16, XOR-swizzled 16B blocks)
//  phase2: h2 = [mean2 | h1(on-the-fly)] @ wt + b2  (MFMA, B from global)
//  phase3: z = relu(h2 @ wh1t + bh1); out = sigmoid(z @ Wh2 + bh2)
__global__ __launch_bounds__(256) void megaG(
    const u32* __restrict__ scp, const int* __restrict__ rowptr,
    const int* __restrict__ col, const u16* __restrict__ wt,
    const u16* __restrict__ wh1t, const float* __restrict__ W1l,
    const float* __restrict__ W1r, const float* __restrict__ b1,
    const float* __restrict__ b2, const float* __restrict__ bh1,
    const float* __restrict__ Wh2, const float* __restrict__ bh2,
    float* __restrict__ out) {
  __shared__ u16 tile[128 * 128];   // 32 KB; holds mean2, then h2, then z
  int tid = threadIdx.x;
  int w = tid >> 6, lane = tid & 63;
  int blockRow = blockIdx.x * 128;

  // ---- phase 1: gather mean2 rows for this wave's 32 nodes
  {
    float w1l0 = W1l[lane * 2], w1l1 = W1l[lane * 2 + 1];
    float w1r0 = W1r[lane * 2], w1r1 = W1r[lane * 2 + 1];
    float b10  = b1[lane * 2],  b11  = b1[lane * 2 + 1];
    int nbase = blockRow + w * 32;
    int rpidx = nbase + ((lane < 33) ? lane : 32);
    int rp = rowptr[(rpidx < N_NODES) ? rpidx : N_NODES];
    for (int nl = 0; nl < 32; ++nl) {
      int beg = __shfl(rp, nl, 64), end = __shfl(rp, nl + 1, 64);
      float a0 = 0.f, a1 = 0.f;
      for (int base = beg; base < end; base += 64) {
        int m = end - base; if (m > 64) m = 64;
        int s = (lane < m) ? col[base + lane] : 0;
        u32 pr = (lane < m) ? scp[s] : 0;
        for (int j = 0; j < m; ++j) {
          u32 p = (u32)__shfl((int)pr, j, 64);
          float m1 = bf2f((u16)(p & 0xffff));
          float xx = bf2f((u16)(p >> 16));
          a0 += fmaxf(fmaf(m1, w1l0, fmaf(xx, w1r0, b10)), 0.f);
          a1 += fmaxf(fmaf(m1, w1l1, fmaf(xx, w1r1, b11)), 0.f);
        }
      }
      float inv = 1.0f / fmaxf((float)(end - beg), 1.0f);
      int row = w * 32 + nl;
      u32 v = (u32)f2bf(a0 * inv) | ((u32)f2bf(a1 * inv) << 16);
      *(u32*)&tile[row * 128 + (((lane >> 2) ^ (row & 15)) << 3) + (lane & 3) * 2] = v;
    }
  }
  __syncthreads();

  // ---- phase 2: gemm1 over K=256 (ks<4: mean2 from LDS; ks>=4: h1 on the fly)
  int n15 = lane & 15, q = lane >> 4;
  frag_cd zero = {0.f, 0.f, 0.f, 0.f};
  frag_cd acc[2][8];
#pragma unroll
  for (int mt = 0; mt < 2; ++mt)
#pragma unroll
    for (int ct = 0; ct < 8; ++ct) acc[mt][ct] = zero;
  u32 pm[2];
#pragma unroll
  for (int mt = 0; mt < 2; ++mt) {
    int r = blockRow + w * 32 + mt * 16 + n15;
    pm[mt] = scp[(r < N_NODES) ? r : (N_NODES - 1)];
  }
#pragma unroll
  for (int ks = 0; ks < 8; ++ks) {
    frag_ab a[2];
    if (ks < 4) {
#pragma unroll
      for (int mt = 0; mt < 2; ++mt) {
        int rl = w * 32 + mt * 16 + n15;
        a[mt] = *(const frag_ab*)&tile[rl * 128 + (((ks * 4 + q) ^ n15) << 3)];
      }
    } else {
      float wf[8], rf[8], bf[8];
      int k0 = (ks - 4) * 32 + q * 8;
#pragma unroll
      for (int j = 0; j < 8; ++j) { wf[j] = W1l[k0 + j]; rf[j] = W1r[k0 + j]; bf[j] = b1[k0 + j]; }
#pragma unroll
      for (int mt = 0; mt < 2; ++mt) {
        float m1 = bf2f((u16)(pm[mt] & 0xffff));
        float xx = bf2f((u16)(pm[mt] >> 16));
        union { frag_ab f; short s[8]; } u;
#pragma unroll
        for (int j = 0; j < 8; ++j)
          u.s[j] = (short)f2bf(fmaxf(fmaf(m1, wf[j], fmaf(xx, rf[j], bf[j])), 0.f));
        a[mt] = u.f;
      }
    }
#pragma unroll
    for (int ct = 0; ct < 8; ++ct) {
      frag_ab b = *(const frag_ab*)&wt[(ct * 16 + n15) * 256 + ks * 32 + q * 8];
#pragma unroll
      for (int mt = 0; mt < 2; ++mt)
        acc[mt][ct] = __builtin_amdgcn_mfma_f32_16x16x32_bf16(a[mt], b, acc[mt][ct], 0, 0, 0);
    }
  }
  __syncthreads();   // all mean2 reads done; safe to overwrite tile with h2

  // epilogue: h2 -> tile (bf16, same swizzle). C/D layout: col=lane&15, row=q*4+r
#pragma unroll
  for (int ct = 0; ct < 8; ++ct) {
    int colg = ct * 16 + n15;
    float bias = b2[colg];
    int kb = colg >> 3;
#pragma unroll
    for (int mt = 0; mt < 2; ++mt) {
      int rbase = w * 32 + mt * 16 + q * 4;
#pragma unroll
      for (int r = 0; r < 4; ++r) {
        int rl = rbase + r;
        tile[rl * 128 + ((kb ^ (rl & 15)) << 3) + (colg & 7)] = f2bf(acc[mt][ct][r] + bias);
      }
    }
  }
  __syncthreads();

  // ---- phase 3: head. z = relu(h2 @ wh1t + bh1), K=128, 64 cols
  frag_cd zacc[2][4];
#pragma unroll
  for (int mt = 0; mt < 2; ++mt)
#pragma unroll
    for (int ct = 0; ct < 4; ++ct) zacc[mt][ct] = zero;
#pragma unroll
  for (int ks = 0; ks < 4; ++ks) {
    frag_ab a[2];
#pragma unroll
    for (int mt = 0; mt < 2; ++mt) {
      int rl = w * 32 + mt * 16 + n15;
      a[mt] = *(const frag_ab*)&tile[rl * 128 + (((ks * 4 + q) ^ n15) << 3)];
    }
#pragma unroll
    for (int ct = 0; ct < 4; ++ct) {
      frag_ab b = *(const frag_ab*)&wh1t[(ct * 16 + n15) * 128 + ks * 32 + q * 8];
#pragma unroll
      for (int mt = 0; mt < 2; ++mt)
        zacc[mt][ct] = __builtin_amdgcn_mfma_f32_16x16x32_bf16(a[mt], b, zacc[mt][ct], 0, 0, 0);
    }
  }
  __syncthreads();   // h2 reads done; overwrite tile with z (stride 68)
  u16* zt = tile;
#pragma unroll
  for (int ct = 0; ct < 4; ++ct) {
    int colg = ct * 16 + n15;
    float bias = bh1[colg];
#pragma unroll
    for (int mt = 0; mt < 2; ++mt) {
      int rbase = w * 32 + mt * 16 + q * 4;
#pragma unroll
      for (int r = 0; r < 4; ++r)
        zt[(rbase + r) * 68 + colg] = f2bf(fmaxf(zacc[mt][ct][r] + bias, 0.0f));
    }
  }
  __syncthreads();
  if (tid < 128) {
    int row = blockRow + tid;
    if (row < N_NODES) {
      float s = bh2[0];
#pragma unroll
      for (int k = 0; k < 64; ++k) s += bf2f(zt[tid * 68 + k]) * Wh2[k];
      out[row] = 1.0f / (1.0f + expf(-s));
    }
  }
}

extern "C" void kernel_launch(void* const* d_in, const int* in_sizes, int n_in,
                              void* d_out, int out_size, void* d_ws, size_t ws_size,
                              hipStream_t stream) {
  const float* x   = (const float*)d_in[0];
  const int*   ei  = (const int*)d_in[1];
  const float* W1l = (const float*)d_in[2];
  const float* W1r = (const float*)d_in[3];
  const float* b1  = (const float*)d_in[4];
  const float* W2l = (const float*)d_in[5];
  const float* W2r = (const float*)d_in[6];
  const float* b2  = (const float*)d_in[7];
  const float* Wh1 = (const float*)d_in[8];
  const float* bh1 = (const float*)d_in[9];
  const float* Wh2 = (const float*)d_in[10];
  const float* bh2 = (const float*)d_in[11];
  float* out = (float*)d_out;

  char* ws = (char*)d_ws;
  size_t off = 0;
  auto alloc = [&](size_t bytes) -> char* {
    char* p = ws + off;
    off += (bytes + 255) & ~(size_t)255;
    return p;
  };
  int*   cnt    = (int*)alloc(N_NODES * 4);
  float* aggx   = (float*)alloc(N_NODES * 4);
  int*   cursor = (int*)alloc(N_NODES * 4);
  size_t zero_bytes = off;                      // cnt+aggx+cursor contiguous
  int*   rowptr = (int*)alloc((N_NODES + 1) * 4);
  int*   col    = (int*)alloc(N_EDGES * 4);
  int*   bsum   = (int*)alloc(NBLK * 4);
  int*   bpre   = (int*)alloc(NBLK * 4);
  u32*   scp    = (u32*)alloc(N_NODES * 4);
  u16*   wt     = (u16*)alloc(65536);
  u16*   wh1t   = (u16*)alloc(16384);
  (void)ws_size; (void)in_sizes; (void)n_in; (void)out_size;

  hipMemsetAsync(ws, 0, zero_bytes, stream);
  hist_pack<<<HIST_BLOCKS + 160, 256, 0, stream>>>(ei, x, W2l, W2r, Wh1, aggx, cnt, wt, wh1t);
  scan_pass1<<<NBLK, 256, 0, stream>>>(cnt, bsum);
  scan_partials<<<1, 512, 0, stream>>>(bsum, bpre, rowptr);
  scan3_scp<<<NBLK * 2, 256, 0, stream>>>(cnt, bpre, aggx, x, rowptr, scp);
  edge_scatter<<<HIST_BLOCKS, 256, 0, stream>>>(ei, rowptr, cursor, col);
  megaG<<<(N_NODES + 127) / 128, 256, 0, stream>>>(scp, rowptr, col, wt, wh1t,
                                                   W1l, W1r, b1, b2, bh1, Wh2, bh2, out);
}